// Round 1
// baseline (1010.986 us; speedup 1.0000x reference)
//
#include <hip/hip_runtime.h>
#include <math.h>

// ---------------- constants ----------------
#define NIMG   4
#define NPROP  2048
#define MTOT   8192          // NIMG*NPROP
#define FIN    12544
#define HID    1024
#define NC     91            // classes incl background
#define NCB    512           // padded combined cls(91)+bbox(364)=455 -> 512
#define DETS   100
#define CAPMAX (NPROP * (NC - 1))   // 184320 per image
#define VLDS   2560          // NMS LDS-resident candidate capacity (6*4*2560 = 61.4 KB)

typedef __attribute__((ext_vector_type(8))) short short8;
typedef __attribute__((ext_vector_type(4))) float f32x4;

__device__ __forceinline__ unsigned short f2bf(float f) {
  union { float f; unsigned u; } v; v.f = f;
  unsigned r = v.u + 0x7fffu + ((v.u >> 16) & 1u);  // RNE
  return (unsigned short)(r >> 16);
}

// pack 2 fp32 -> 2 bf16 (RNE) in one VALU op
__device__ __forceinline__ unsigned cvtpk(float lo, float hi) {
  unsigned r;
  asm("v_cvt_pk_bf16_f32 %0, %1, %2" : "=v"(r) : "v"(lo), "v"(hi));
  return r;
}

// async global->LDS, 16B per lane; lds dest must be wave-uniform base (+lane*16 in HW)
__device__ __forceinline__ void gload_lds16(const void* g, void* l) {
  __builtin_amdgcn_global_load_lds((__attribute__((address_space(1))) void*)(g),
                                   (__attribute__((address_space(3))) void*)(l), 16, 0, 0);
}

// ---------------- transpose + fp32->bf16 convert ----------------
// in: [K][N] fp32 row-major; out: [row_off + n][k] bf16, leading dim out_ld
__global__ void transpose_cvt(const float* __restrict__ in, unsigned short* __restrict__ out,
                              int K, int N, int row_off, int out_ld) {
  __shared__ float tile[32][33];
  int k0 = blockIdx.y * 32, n0 = blockIdx.x * 32;
  int tx = threadIdx.x, ty = threadIdx.y;
#pragma unroll
  for (int i = 0; i < 4; ++i) {
    int r = ty + i * 8;
    if (k0 + r < K && n0 + tx < N)
      tile[r][tx] = in[(size_t)(k0 + r) * N + (n0 + tx)];
  }
  __syncthreads();
#pragma unroll
  for (int i = 0; i < 4; ++i) {
    int r = ty + i * 8;
    if (n0 + r < N && k0 + tx < K)
      out[(size_t)(row_off + n0 + r) * out_ld + (k0 + tx)] = f2bf(tile[tx][r]);
  }
}

// zero pad rows of Wcbt, build combined bias, zero candidate counters
__global__ void prep_misc(unsigned short* __restrict__ Wcbt, float* __restrict__ bias_cb,
                          const float* __restrict__ cls_b, const float* __restrict__ bbox_b,
                          int* __restrict__ ccount) {
  int i = blockIdx.x * blockDim.x + threadIdx.x;
  int stride = gridDim.x * blockDim.x;
  for (int j = i; j < 57 * 1024; j += stride) Wcbt[455 * 1024 + j] = 0;          // pad rows 455..511
  for (int j = i; j < NCB; j += stride)
    bias_cb[j] = (j < 91) ? cls_b[j] : ((j < 455) ? bbox_b[j - 91] : 0.0f);
  if (i < NIMG) ccount[i] = 0;
}

// ---------------- NT GEMM: C[m][n] = act(sum_k A[m][k]*Bt[n][k] + bias[n]) ----------------
// m97 structure: 128x128 tile, BK=64, linear LDS [128][64], global_load_lds staging (B always;
// A too when bf16), 4 waves (2x2), each wave 64x64 via 4x4 mfma_16x16x32_bf16.
template <bool AFP32, bool RELU, bool OUTBF16>
__global__ __launch_bounds__(256) void gemm_nt(const void* __restrict__ Av,
                                               const unsigned short* __restrict__ Bt,
                                               const float* __restrict__ bias,
                                               void* __restrict__ Cv,
                                               int M, int N, int K) {
  // linear layout (no pad) — required for global_load_lds contiguous dest (m104)
  __shared__ __align__(16) unsigned short As[128 * 64];
  __shared__ __align__(16) unsigned short Bs[128 * 64];
  const int tid  = threadIdx.x;
  const int lane = tid & 63;
  const int wid  = tid >> 6;
  const int wm   = (wid >> 1) * 64;
  const int wn   = (wid & 1) * 64;
  const int m0   = blockIdx.y * 128, n0 = blockIdx.x * 128;
  const int lcol = lane & 15;
  const int lk8  = (lane >> 4) * 8;

  f32x4 acc[4][4];
#pragma unroll
  for (int a = 0; a < 4; ++a)
#pragma unroll
    for (int b = 0; b < 4; ++b)
#pragma unroll
      for (int r = 0; r < 4; ++r) acc[a][b][r] = 0.0f;

  // staging geometry for gload_lds: chunk = 1KB = 8 rows x 64 k (bf16);
  // per wave 4 chunks; lane covers row = chunk*8 + lane/8, kc = (lane&7)*8 elems.
  const int st_r  = lane >> 3;
  const int st_kc = (lane & 7) << 3;

  for (int k0 = 0; k0 < K; k0 += 64) {
    // ---- issue async B staging first ----
#pragma unroll
    for (int i = 0; i < 4; ++i) {
      int chunk = (wid << 2) | i;
      int r = (chunk << 3) | st_r;
      gload_lds16(Bt + (size_t)(n0 + r) * K + k0 + st_kc, Bs + (chunk << 9));
    }
    if constexpr (AFP32) {
      // reg-stage A: fp32 load + packed cvt + ds_write (256 thr x 4 slots x 8 elems = 128x64)
#pragma unroll
      for (int i = 0; i < 4; ++i) {
        int s   = tid + (i << 8);
        int row = s >> 3;
        int kc  = (s & 7) << 3;
        const float* gp = (const float*)Av + (size_t)(m0 + row) * K + (k0 + kc);
        float4 u = *(const float4*)gp;
        float4 w = *(const float4*)(gp + 4);
        union { unsigned u32[4]; short8 s8; } pk;
        pk.u32[0] = cvtpk(u.x, u.y);
        pk.u32[1] = cvtpk(u.z, u.w);
        pk.u32[2] = cvtpk(w.x, w.y);
        pk.u32[3] = cvtpk(w.z, w.w);
        *(short8*)&As[row * 64 + kc] = pk.s8;
      }
    } else {
#pragma unroll
      for (int i = 0; i < 4; ++i) {
        int chunk = (wid << 2) | i;
        int r = (chunk << 3) | st_r;
        gload_lds16((const unsigned short*)Av + (size_t)(m0 + r) * K + k0 + st_kc,
                    As + (chunk << 9));
      }
    }
    __syncthreads();
    // ---- compute: 2 K-steps of 32 ----
#pragma unroll
    for (int kk = 0; kk < 64; kk += 32) {
      short8 af[4], bf[4];
#pragma unroll
      for (int im = 0; im < 4; ++im)
        af[im] = *(const short8*)&As[(wm + im * 16 + lcol) * 64 + kk + lk8];
#pragma unroll
      for (int in = 0; in < 4; ++in)
        bf[in] = *(const short8*)&Bs[(wn + in * 16 + lcol) * 64 + kk + lk8];
#pragma unroll
      for (int im = 0; im < 4; ++im)
#pragma unroll
        for (int in = 0; in < 4; ++in)
          acc[im][in] = __builtin_amdgcn_mfma_f32_16x16x32_bf16(af[im], bf[in], acc[im][in], 0, 0, 0);
    }
    __syncthreads();
  }

  // ---- epilogue: C/D layout col=lane&15, row=(lane>>4)*4+r ----
  const int r0 = (lane >> 4) * 4;
#pragma unroll
  for (int im = 0; im < 4; ++im) {
#pragma unroll
    for (int in = 0; in < 4; ++in) {
      int gn = n0 + wn + in * 16 + lcol;
      float bv = bias[gn];
#pragma unroll
      for (int r = 0; r < 4; ++r) {
        int gm = m0 + wm + im * 16 + r0 + r;
        float vv = acc[im][in][r] + bv;
        if (RELU) vv = fmaxf(vv, 0.0f);
        if (OUTBF16) ((unsigned short*)Cv)[(size_t)gm * N + gn] = f2bf(vv);
        else         ((float*)Cv)[(size_t)gm * N + gn] = vv;
      }
    }
  }
}

// ---------------- candidate generation: one WAVE per proposal ----------------
// 64 lanes cover 91 classes (lane -> class lane, class 64+lane for lane<27).
__global__ void candgen(const float* __restrict__ out3, const float* __restrict__ props,
                        float* __restrict__ cscore, float* __restrict__ cbox,
                        int* __restrict__ clabel, int* __restrict__ ccount, int CAP) {
  int gw   = (blockIdx.x * blockDim.x + threadIdx.x) >> 6;   // proposal index
  int lane = threadIdx.x & 63;
  if (gw >= MTOT) return;
  int img = gw >> 11;
  const float* row = out3 + (size_t)gw * NCB;

  float l0 = row[lane];                                    // classes 0..63
  float l1 = (lane < NC - 64) ? row[64 + lane] : -INFINITY; // classes 64..90
  float mx = fmaxf(l0, l1);
#pragma unroll
  for (int off = 32; off; off >>= 1) mx = fmaxf(mx, __shfl_xor(mx, off));
  float e0 = expf(l0 - mx);
  float e1 = (lane < NC - 64) ? expf(l1 - mx) : 0.0f;
  float den = e0 + e1;
#pragma unroll
  for (int off = 32; off; off >>= 1) den += __shfl_xor(den, off);
  float inv = 1.0f / den;

  float4 p = *(const float4*)(props + (size_t)gw * 4);
  float w = p.z - p.x, h = p.w - p.y;
  float cx = p.x + 0.5f * w, cy = p.y + 0.5f * h;

#pragma unroll
  for (int half = 0; half < 2; ++half) {
    int c = (half << 6) + lane;
    float s = (half ? e1 : e0) * inv;
    if (c >= 1 && c < NC && s > 0.05f) {
      float dx = row[91 + c * 4 + 0] * 0.1f;
      float dy = row[91 + c * 4 + 1] * 0.1f;
      float dw = fminf(row[91 + c * 4 + 2] * 0.2f, 4.135166556742356f);
      float dh = fminf(row[91 + c * 4 + 3] * 0.2f, 4.135166556742356f);
      float pcx = dx * w + cx, pcy = dy * h + cy;
      float pw = expf(dw) * w, ph = expf(dh) * h;
      float x1 = fminf(fmaxf(pcx - 0.5f * pw, 0.0f), 800.0f);
      float x2 = fminf(fmaxf(pcx + 0.5f * pw, 0.0f), 800.0f);
      float y1 = fminf(fmaxf(pcy - 0.5f * ph, 0.0f), 800.0f);
      float y2 = fminf(fmaxf(pcy + 0.5f * ph, 0.0f), 800.0f);
      if (x2 - x1 >= 0.01f && y2 - y1 >= 0.01f) {
        int idx = atomicAdd(&ccount[img], 1);
        if (idx < CAP) {
          size_t o = (size_t)img * CAP + idx;
          cscore[o] = s;
          clabel[o] = c;
          cbox[o * 4 + 0] = x1; cbox[o * 4 + 1] = y1;
          cbox[o * 4 + 2] = x2; cbox[o * 4 + 3] = y2;
        }
      }
    }
  }
}

// ---------------- sequential NMS; one block per image; LDS-resident candidates ----------------
__global__ __launch_bounds__(256) void nms_kernel(float* __restrict__ cscore, const float* __restrict__ cbox,
                           const int* __restrict__ clabel, const int* __restrict__ ccount,
                           float* __restrict__ out, int CAP) {
  int img = blockIdx.x;
  int tid = threadIdx.x;
  int lane = tid & 63, wid = tid >> 6;
  int V = ccount[img]; if (V > CAP) V = CAP;
  int VL = V < VLDS ? V : VLDS;
  float* sc = cscore + (size_t)img * CAP;
  const float* bx = cbox + (size_t)img * CAP * 4;
  const int* lb = clabel + (size_t)img * CAP;
  float* ob  = out + (size_t)img * DETS * 4;                       // boxes  [4,100,4]
  float* osd = out + (size_t)NIMG * DETS * 4 + (size_t)img * DETS; // scores [4,100]
  float* ol  = out + (size_t)NIMG * DETS * 5 + (size_t)img * DETS; // labels [4,100]

  for (int t = tid; t < DETS; t += blockDim.x) {
    ob[t * 4 + 0] = 0.0f; ob[t * 4 + 1] = 0.0f; ob[t * 4 + 2] = 0.0f; ob[t * 4 + 3] = 0.0f;
    osd[t] = 0.0f; ol[t] = 0.0f;
  }

  __shared__ float sx1[VLDS], sy1[VLDS], sx2[VLDS], sy2[VLDS], sar[VLDS], ssc[VLDS];
  __shared__ float rs[4]; __shared__ int ri[4];
  __shared__ float bbs[6];
  __shared__ int   bbest;

  // load + precompute offset boxes and areas once
  for (int t = tid; t < VL; t += blockDim.x) {
    float4 b = *(const float4*)&bx[(size_t)t * 4];
    float offv = (float)lb[t] * 801.0f;
    sx1[t] = b.x + offv; sy1[t] = b.y + offv;
    sx2[t] = b.z + offv; sy2[t] = b.w + offv;
    sar[t] = (b.z - b.x) * (b.w - b.y);     // area is offset-invariant
    ssc[t] = sc[t];
  }
  __syncthreads();

  for (int d = 0; d < DETS; ++d) {
    // ---- argmax over remaining scores ----
    float bs = -INFINITY; int bi = -1;
    for (int t = tid; t < VL; t += blockDim.x) { float v = ssc[t]; if (v > bs) { bs = v; bi = t; } }
    if (V > VLDS)
      for (int t = VLDS + tid; t < V; t += blockDim.x) { float v = sc[t]; if (v > bs) { bs = v; bi = t; } }
#pragma unroll
    for (int off = 32; off; off >>= 1) {
      float osf = __shfl_xor(bs, off); int oi = __shfl_xor(bi, off);
      if (osf > bs) { bs = osf; bi = oi; }
    }
    if (lane == 0) { rs[wid] = bs; ri[wid] = bi; }
    __syncthreads();
    if (tid == 0) {
      float b0 = rs[0]; int i0 = ri[0];
      for (int wv = 1; wv < 4; ++wv) if (rs[wv] > b0) { b0 = rs[wv]; i0 = ri[wv]; }
      if (i0 < 0 || !(b0 > -INFINITY)) {
        bbest = -1;
      } else {
        bbest = i0;
        float ox1, oy1, ox2, oy2, ar;
        if (i0 < VLDS) { ox1 = sx1[i0]; oy1 = sy1[i0]; ox2 = sx2[i0]; oy2 = sy2[i0]; ar = sar[i0]; }
        else {
          float4 b = *(const float4*)&bx[(size_t)i0 * 4];
          float offv = (float)lb[i0] * 801.0f;
          ox1 = b.x + offv; oy1 = b.y + offv; ox2 = b.z + offv; oy2 = b.w + offv;
          ar = (b.z - b.x) * (b.w - b.y);
        }
        bbs[0] = ox1; bbs[1] = oy1; bbs[2] = ox2; bbs[3] = oy2; bbs[4] = ar;
        float4 rb = *(const float4*)&bx[(size_t)i0 * 4];
        ob[d * 4 + 0] = rb.x; ob[d * 4 + 1] = rb.y; ob[d * 4 + 2] = rb.z; ob[d * 4 + 3] = rb.w;
        osd[d] = b0;
        ol[d] = (float)lb[i0];
      }
    }
    __syncthreads();
    if (bbest < 0) break;   // uniform: remaining outputs already zeroed
    float bx1 = bbs[0], by1 = bbs[1], bx2 = bbs[2], by2 = bbs[3], barea = bbs[4];
    // ---- suppress ----
    for (int t = tid; t < VL; t += blockDim.x) {
      float ltx = fmaxf(sx1[t], bx1), lty = fmaxf(sy1[t], by1);
      float rbx = fminf(sx2[t], bx2), rby = fminf(sy2[t], by2);
      float inter = fmaxf(rbx - ltx, 0.0f) * fmaxf(rby - lty, 0.0f);
      float uni = fmaxf(sar[t] + barea - inter, 1e-6f);
      if (inter / uni > 0.5f) ssc[t] = -INFINITY;
    }
    if (V > VLDS) {
      for (int t = VLDS + tid; t < V; t += blockDim.x) {
        float4 b = *(const float4*)&bx[(size_t)t * 4];
        float offv = (float)lb[t] * 801.0f;
        float tx1 = b.x + offv, ty1 = b.y + offv, tx2 = b.z + offv, ty2 = b.w + offv;
        float ltx = fmaxf(tx1, bx1), lty = fmaxf(ty1, by1);
        float rbx = fminf(tx2, bx2), rby = fminf(ty2, by2);
        float inter = fmaxf(rbx - ltx, 0.0f) * fmaxf(rby - lty, 0.0f);
        float areat = (tx2 - tx1) * (ty2 - ty1);
        float uni = fmaxf(areat + barea - inter, 1e-6f);
        if (inter / uni > 0.5f) sc[t] = -INFINITY;
      }
    }
    __syncthreads();
  }
}

// ---------------- host ----------------
extern "C" void kernel_launch(void* const* d_in, const int* in_sizes, int n_in,
                              void* d_out, int out_size, void* d_ws, size_t ws_size,
                              hipStream_t stream) {
  const float* box_features = (const float*)d_in[0];
  const float* proposals    = (const float*)d_in[1];
  const float* fc6_w = (const float*)d_in[2];
  const float* fc6_b = (const float*)d_in[3];
  const float* fc7_w = (const float*)d_in[4];
  const float* fc7_b = (const float*)d_in[5];
  const float* cls_w = (const float*)d_in[6];
  const float* cls_b = (const float*)d_in[7];
  const float* bbox_w = (const float*)d_in[8];
  const float* bbox_b = (const float*)d_in[9];

  char* ws = (char*)d_ws;
  size_t off = 0;
  unsigned short* W6t  = (unsigned short*)(ws + off); off += (size_t)HID * FIN * 2;   // 25.7 MB
  unsigned short* W7t  = (unsigned short*)(ws + off); off += (size_t)HID * HID * 2;   // 2 MB
  unsigned short* Wcbt = (unsigned short*)(ws + off); off += (size_t)NCB * HID * 2;   // 1 MB
  float* bias_cb       = (float*)(ws + off);          off += (size_t)NCB * 4;
  int*   ccount        = (int*)(ws + off);            off += 256;
  unsigned short* h1   = (unsigned short*)(ws + off); off += (size_t)MTOT * HID * 2;  // 16 MB
  unsigned short* h2   = (unsigned short*)(ws + off); off += (size_t)MTOT * HID * 2;  // 16 MB
  float* out3          = (float*)(ws + off);          off += (size_t)MTOT * NCB * 4;  // 16 MB

  // candidate arrays sized by remaining workspace (96 B per candidate across 4 images)
  int CAP = CAPMAX;
  if (ws_size > off) {
    size_t avail = ws_size - off;
    size_t cap_ws = avail / 96;
    if (cap_ws < (size_t)CAP) CAP = (int)cap_ws;
  } else {
    CAP = 0;
  }
  float* cscore = (float*)(ws + off);
  int*   clabel = (int*)(ws + off + (size_t)NIMG * CAP * 4);
  float* cbox   = (float*)(ws + off + (size_t)NIMG * CAP * 8);

  // ---- weight prep ----
  transpose_cvt<<<dim3(HID / 32, FIN / 32), dim3(32, 8), 0, stream>>>(fc6_w, W6t, FIN, HID, 0, FIN);
  transpose_cvt<<<dim3(HID / 32, HID / 32), dim3(32, 8), 0, stream>>>(fc7_w, W7t, HID, HID, 0, HID);
  transpose_cvt<<<dim3(3,  HID / 32), dim3(32, 8), 0, stream>>>(cls_w,  Wcbt, HID, 91,  0,  HID);
  transpose_cvt<<<dim3(12, HID / 32), dim3(32, 8), 0, stream>>>(bbox_w, Wcbt, HID, 364, 91, HID);
  prep_misc<<<64, 256, 0, stream>>>(Wcbt, bias_cb, cls_b, bbox_b, ccount);

  // ---- MLP head + predictor ----
  // grid.x = n-tiles (fastest) so blocks sharing an A-slab co-run -> A HBM-read ~once via L3
  gemm_nt<true,  true,  true ><<<dim3(HID / 128, MTOT / 128), 256, 0, stream>>>(
      box_features, W6t, fc6_b, h1, MTOT, HID, FIN);
  gemm_nt<false, true,  true ><<<dim3(HID / 128, MTOT / 128), 256, 0, stream>>>(
      h1, W7t, fc7_b, h2, MTOT, HID, HID);
  gemm_nt<false, false, false><<<dim3(NCB / 128, MTOT / 128), 256, 0, stream>>>(
      h2, Wcbt, bias_cb, out3, MTOT, NCB, HID);

  // ---- postprocess ----
  candgen<<<(MTOT * 64) / 256, 256, 0, stream>>>(out3, proposals, cscore, cbox, clabel, ccount, CAP);
  nms_kernel<<<NIMG, 256, 0, stream>>>(cscore, cbox, clabel, ccount, (float*)d_out, CAP);
}

// Round 2
// 879.064 us; speedup vs baseline: 1.1501x; 1.1501x over previous
//
#include <hip/hip_runtime.h>
#include <math.h>

// ---------------- constants ----------------
#define NIMG   4
#define NPROP  2048
#define MTOT   8192          // NIMG*NPROP
#define FIN    12544
#define HID    1024
#define NC     91            // classes incl background
#define NCB    512           // padded combined cls(91)+bbox(364)=455 -> 512
#define DETS   100
#define CAPMAX (NPROP * (NC - 1))   // 184320 per image
#define VLDS   2560          // NMS LDS-resident candidate capacity

typedef __attribute__((ext_vector_type(8))) short short8;
typedef __attribute__((ext_vector_type(4))) float f32x4;

__device__ __forceinline__ unsigned short f2bf(float f) {
  union { float f; unsigned u; } v; v.f = f;
  unsigned r = v.u + 0x7fffu + ((v.u >> 16) & 1u);  // RNE
  return (unsigned short)(r >> 16);
}

// pack 2 fp32 -> 2 bf16 (RNE) in one VALU op
__device__ __forceinline__ unsigned cvtpk(float lo, float hi) {
  unsigned r;
  asm("v_cvt_pk_bf16_f32 %0, %1, %2" : "=v"(r) : "v"(lo), "v"(hi));
  return r;
}

// async global->LDS, 16B per lane; lds dest is wave-uniform base (+lane*16 in HW)
__device__ __forceinline__ void gload_lds16(const void* g, void* l) {
  __builtin_amdgcn_global_load_lds((__attribute__((address_space(1))) void*)(g),
                                   (__attribute__((address_space(3))) void*)(l), 16, 0, 0);
}

// ---------------- transpose + fp32->bf16 convert ----------------
__global__ void transpose_cvt(const float* __restrict__ in, unsigned short* __restrict__ out,
                              int K, int N, int row_off, int out_ld) {
  __shared__ float tile[32][33];
  int k0 = blockIdx.y * 32, n0 = blockIdx.x * 32;
  int tx = threadIdx.x, ty = threadIdx.y;
#pragma unroll
  for (int i = 0; i < 4; ++i) {
    int r = ty + i * 8;
    if (k0 + r < K && n0 + tx < N)
      tile[r][tx] = in[(size_t)(k0 + r) * N + (n0 + tx)];
  }
  __syncthreads();
#pragma unroll
  for (int i = 0; i < 4; ++i) {
    int r = ty + i * 8;
    if (n0 + r < N && k0 + tx < K)
      out[(size_t)(row_off + n0 + r) * out_ld + (k0 + tx)] = f2bf(tile[tx][r]);
  }
}

// zero pad rows of Wcbt, build combined bias, zero candidate counters
__global__ void prep_misc(unsigned short* __restrict__ Wcbt, float* __restrict__ bias_cb,
                          const float* __restrict__ cls_b, const float* __restrict__ bbox_b,
                          int* __restrict__ ccount) {
  int i = blockIdx.x * blockDim.x + threadIdx.x;
  int stride = gridDim.x * blockDim.x;
  for (int j = i; j < 57 * 1024; j += stride) Wcbt[455 * 1024 + j] = 0;
  for (int j = i; j < NCB; j += stride)
    bias_cb[j] = (j < 91) ? cls_b[j] : ((j < 455) ? bbox_b[j - 91] : 0.0f);
  if (i < NIMG) ccount[i] = 0;
}

// ---------------- NT GEMM: C[m][n] = act(sum_k A[m][k]*Bt[n][k] + bias[n]) ----------------
// 128x128 tile, BK=64, double-buffered LDS, XOR-swizzled layout (LDS[row][s] = G[row][s^(row&7)],
// 16B slots), prefetch-before-compute. Grid: blockIdx.x = m-tile (fastest) so the blocks sharing
// an A-slab land on the same XCD (linear%8 == m%8) -> slab served from one L2.
template <bool AFP32, bool RELU, bool OUTBF16>
__global__ __launch_bounds__(256) void gemm_nt(const void* __restrict__ Av,
                                               const unsigned short* __restrict__ Bt,
                                               const float* __restrict__ bias,
                                               void* __restrict__ Cv,
                                               int M, int N, int K) {
  __shared__ __align__(16) unsigned short As[2][128 * 64];
  __shared__ __align__(16) unsigned short Bs[2][128 * 64];
  const int tid  = threadIdx.x;
  const int lane = tid & 63;
  const int wid  = tid >> 6;
  const int wm   = (wid >> 1) * 64;
  const int wn   = (wid & 1) * 64;
  const int m0   = blockIdx.x * 128, n0 = blockIdx.y * 128;
  const int lcol = lane & 15;
  const int lk4  = lane >> 4;        // frag slot sub-index 0..3
  const int rsw  = lcol & 7;         // row&7 for swizzled frag reads

  // staging geometry: chunk = 1KB = 8 rows x 8 slots(16B); lane covers row chunk*8+(lane>>3),
  // LDS slot lane&7. Source column pre-swizzled so linear LDS dest yields swizzled layout.
  const int st_r  = lane >> 3;
  const int st_kc = ((lane & 7) ^ st_r) << 3;   // pre-swizzled source column (elements)

  f32x4 acc[4][4];
#pragma unroll
  for (int a = 0; a < 4; ++a)
#pragma unroll
    for (int b = 0; b < 4; ++b)
#pragma unroll
      for (int r = 0; r < 4; ++r) acc[a][b][r] = 0.0f;

  const int NT = K >> 6;
  float4 pa[4][2];   // fp32-A prefetch registers

  auto stage_async = [&](int buf, int t) {
    const int k0 = t << 6;
#pragma unroll
    for (int i = 0; i < 4; ++i) {
      int chunk = (wid << 2) | i;
      int r = (chunk << 3) | st_r;
      gload_lds16(Bt + (size_t)(n0 + r) * K + k0 + st_kc, &Bs[buf][chunk << 9]);
      if constexpr (!AFP32)
        gload_lds16((const unsigned short*)Av + (size_t)(m0 + r) * K + k0 + st_kc,
                    &As[buf][chunk << 9]);
    }
  };
  auto loadA = [&](int t) {
    const int k0 = t << 6;
#pragma unroll
    for (int i = 0; i < 4; ++i) {
      int s = tid + (i << 8);
      int row = s >> 3, kc = (s & 7) << 3;
      const float* gp = (const float*)Av + (size_t)(m0 + row) * K + (k0 + kc);
      pa[i][0] = *(const float4*)gp;
      pa[i][1] = *(const float4*)(gp + 4);
    }
  };
  auto writeA = [&](int buf) {
#pragma unroll
    for (int i = 0; i < 4; ++i) {
      int s = tid + (i << 8);
      int row = s >> 3;
      int slot = ((s & 7) ^ (row & 7)) << 3;   // swizzled LDS dest
      union { unsigned u32[4]; short8 s8; } pk;
      pk.u32[0] = cvtpk(pa[i][0].x, pa[i][0].y);
      pk.u32[1] = cvtpk(pa[i][0].z, pa[i][0].w);
      pk.u32[2] = cvtpk(pa[i][1].x, pa[i][1].y);
      pk.u32[3] = cvtpk(pa[i][1].z, pa[i][1].w);
      *(short8*)&As[buf][row * 64 + slot] = pk.s8;
    }
  };

  // ---- prologue: fill buffer 0 ----
  stage_async(0, 0);
  if constexpr (AFP32) { loadA(0); writeA(0); }
  __syncthreads();

  int cur = 0;
  for (int t = 0; t < NT; ++t) {
    const int nxt = cur ^ 1;
    if (t + 1 < NT) {                 // issue next-tile loads BEFORE compute (latency hides)
      stage_async(nxt, t + 1);
      if constexpr (AFP32) loadA(t + 1);
    }
#pragma unroll
    for (int kk = 0; kk < 2; ++kk) {
      const int sb = kk << 2;
      short8 af[4], bf[4];
#pragma unroll
      for (int im = 0; im < 4; ++im)
        af[im] = *(const short8*)&As[cur][(wm + im * 16 + lcol) * 64 + (((sb + lk4) ^ rsw) << 3)];
#pragma unroll
      for (int in = 0; in < 4; ++in)
        bf[in] = *(const short8*)&Bs[cur][(wn + in * 16 + lcol) * 64 + (((sb + lk4) ^ rsw) << 3)];
#pragma unroll
      for (int im = 0; im < 4; ++im)
#pragma unroll
        for (int in = 0; in < 4; ++in)
          acc[im][in] = __builtin_amdgcn_mfma_f32_16x16x32_bf16(af[im], bf[in], acc[im][in], 0, 0, 0);
    }
    if (t + 1 < NT) { if constexpr (AFP32) writeA(nxt); }  // cvt+write after MFMA (T14 split)
    __syncthreads();   // drains vmcnt(gload_lds)+lgkm; next tile ready
    cur = nxt;
  }

  // ---- epilogue: C/D layout col=lane&15, row=(lane>>4)*4+r ----
  const int r0 = (lane >> 4) * 4;
#pragma unroll
  for (int im = 0; im < 4; ++im) {
#pragma unroll
    for (int in = 0; in < 4; ++in) {
      int gn = n0 + wn + in * 16 + lcol;
      float bv = bias[gn];
#pragma unroll
      for (int r = 0; r < 4; ++r) {
        int gm = m0 + wm + im * 16 + r0 + r;
        float vv = acc[im][in][r] + bv;
        if (RELU) vv = fmaxf(vv, 0.0f);
        if (OUTBF16) ((unsigned short*)Cv)[(size_t)gm * N + gn] = f2bf(vv);
        else         ((float*)Cv)[(size_t)gm * N + gn] = vv;
      }
    }
  }
}

// ---------------- candidate generation: one WAVE per proposal ----------------
__global__ void candgen(const float* __restrict__ out3, const float* __restrict__ props,
                        float* __restrict__ cscore, float* __restrict__ cbox,
                        int* __restrict__ clabel, int* __restrict__ ccount, int CAP) {
  int gw   = (blockIdx.x * blockDim.x + threadIdx.x) >> 6;   // proposal index
  int lane = threadIdx.x & 63;
  if (gw >= MTOT) return;
  int img = gw >> 11;
  const float* row = out3 + (size_t)gw * NCB;

  float l0 = row[lane];                                     // classes 0..63
  float l1 = (lane < NC - 64) ? row[64 + lane] : -INFINITY; // classes 64..90
  float mx = fmaxf(l0, l1);
#pragma unroll
  for (int off = 32; off; off >>= 1) mx = fmaxf(mx, __shfl_xor(mx, off));
  float e0 = expf(l0 - mx);
  float e1 = (lane < NC - 64) ? expf(l1 - mx) : 0.0f;
  float den = e0 + e1;
#pragma unroll
  for (int off = 32; off; off >>= 1) den += __shfl_xor(den, off);
  float inv = 1.0f / den;

  float4 p = *(const float4*)(props + (size_t)gw * 4);
  float w = p.z - p.x, h = p.w - p.y;
  float cx = p.x + 0.5f * w, cy = p.y + 0.5f * h;

#pragma unroll
  for (int half = 0; half < 2; ++half) {
    int c = (half << 6) + lane;
    float s = (half ? e1 : e0) * inv;
    if (c >= 1 && c < NC && s > 0.05f) {
      float dx = row[91 + c * 4 + 0] * 0.1f;
      float dy = row[91 + c * 4 + 1] * 0.1f;
      float dw = fminf(row[91 + c * 4 + 2] * 0.2f, 4.135166556742356f);
      float dh = fminf(row[91 + c * 4 + 3] * 0.2f, 4.135166556742356f);
      float pcx = dx * w + cx, pcy = dy * h + cy;
      float pw = expf(dw) * w, ph = expf(dh) * h;
      float x1 = fminf(fmaxf(pcx - 0.5f * pw, 0.0f), 800.0f);
      float x2 = fminf(fmaxf(pcx + 0.5f * pw, 0.0f), 800.0f);
      float y1 = fminf(fmaxf(pcy - 0.5f * ph, 0.0f), 800.0f);
      float y2 = fminf(fmaxf(pcy + 0.5f * ph, 0.0f), 800.0f);
      if (x2 - x1 >= 0.01f && y2 - y1 >= 0.01f) {
        int idx = atomicAdd(&ccount[img], 1);
        if (idx < CAP) {
          size_t o = (size_t)img * CAP + idx;
          cscore[o] = s;
          clabel[o] = c;
          cbox[o * 4 + 0] = x1; cbox[o * 4 + 1] = y1;
          cbox[o * 4 + 2] = x2; cbox[o * 4 + 3] = y2;
        }
      }
    }
  }
}

// ---------------- sequential NMS; one block per image; LDS-resident candidates ----------------
__global__ __launch_bounds__(256) void nms_kernel(float* __restrict__ cscore, const float* __restrict__ cbox,
                           const int* __restrict__ clabel, const int* __restrict__ ccount,
                           float* __restrict__ out, int CAP) {
  int img = blockIdx.x;
  int tid = threadIdx.x;
  int lane = tid & 63, wid = tid >> 6;
  int V = ccount[img]; if (V > CAP) V = CAP;
  int VL = V < VLDS ? V : VLDS;
  float* sc = cscore + (size_t)img * CAP;
  const float* bx = cbox + (size_t)img * CAP * 4;
  const int* lb = clabel + (size_t)img * CAP;
  float* ob  = out + (size_t)img * DETS * 4;
  float* osd = out + (size_t)NIMG * DETS * 4 + (size_t)img * DETS;
  float* ol  = out + (size_t)NIMG * DETS * 5 + (size_t)img * DETS;

  for (int t = tid; t < DETS; t += blockDim.x) {
    ob[t * 4 + 0] = 0.0f; ob[t * 4 + 1] = 0.0f; ob[t * 4 + 2] = 0.0f; ob[t * 4 + 3] = 0.0f;
    osd[t] = 0.0f; ol[t] = 0.0f;
  }

  __shared__ float sx1[VLDS], sy1[VLDS], sx2[VLDS], sy2[VLDS], sar[VLDS], ssc[VLDS];
  __shared__ float rs[4]; __shared__ int ri[4];
  __shared__ float bbs[6];
  __shared__ int   bbest;

  for (int t = tid; t < VL; t += blockDim.x) {
    float4 b = *(const float4*)&bx[(size_t)t * 4];
    float offv = (float)lb[t] * 801.0f;
    sx1[t] = b.x + offv; sy1[t] = b.y + offv;
    sx2[t] = b.z + offv; sy2[t] = b.w + offv;
    sar[t] = (b.z - b.x) * (b.w - b.y);
    ssc[t] = sc[t];
  }
  __syncthreads();

  for (int d = 0; d < DETS; ++d) {
    float bs = -INFINITY; int bi = -1;
    for (int t = tid; t < VL; t += blockDim.x) { float v = ssc[t]; if (v > bs) { bs = v; bi = t; } }
    if (V > VLDS)
      for (int t = VLDS + tid; t < V; t += blockDim.x) { float v = sc[t]; if (v > bs) { bs = v; bi = t; } }
#pragma unroll
    for (int off = 32; off; off >>= 1) {
      float osf = __shfl_xor(bs, off); int oi = __shfl_xor(bi, off);
      if (osf > bs) { bs = osf; bi = oi; }
    }
    if (lane == 0) { rs[wid] = bs; ri[wid] = bi; }
    __syncthreads();
    if (tid == 0) {
      float b0 = rs[0]; int i0 = ri[0];
      for (int wv = 1; wv < 4; ++wv) if (rs[wv] > b0) { b0 = rs[wv]; i0 = ri[wv]; }
      if (i0 < 0 || !(b0 > -INFINITY)) {
        bbest = -1;
      } else {
        bbest = i0;
        float ox1, oy1, ox2, oy2, ar;
        if (i0 < VLDS) { ox1 = sx1[i0]; oy1 = sy1[i0]; ox2 = sx2[i0]; oy2 = sy2[i0]; ar = sar[i0]; }
        else {
          float4 b = *(const float4*)&bx[(size_t)i0 * 4];
          float offv = (float)lb[i0] * 801.0f;
          ox1 = b.x + offv; oy1 = b.y + offv; ox2 = b.z + offv; oy2 = b.w + offv;
          ar = (b.z - b.x) * (b.w - b.y);
        }
        bbs[0] = ox1; bbs[1] = oy1; bbs[2] = ox2; bbs[3] = oy2; bbs[4] = ar;
        float4 rb = *(const float4*)&bx[(size_t)i0 * 4];
        ob[d * 4 + 0] = rb.x; ob[d * 4 + 1] = rb.y; ob[d * 4 + 2] = rb.z; ob[d * 4 + 3] = rb.w;
        osd[d] = b0;
        ol[d] = (float)lb[i0];
      }
    }
    __syncthreads();
    if (bbest < 0) break;
    float bx1 = bbs[0], by1 = bbs[1], bx2 = bbs[2], by2 = bbs[3], barea = bbs[4];
    for (int t = tid; t < VL; t += blockDim.x) {
      float ltx = fmaxf(sx1[t], bx1), lty = fmaxf(sy1[t], by1);
      float rbx = fminf(sx2[t], bx2), rby = fminf(sy2[t], by2);
      float inter = fmaxf(rbx - ltx, 0.0f) * fmaxf(rby - lty, 0.0f);
      float uni = fmaxf(sar[t] + barea - inter, 1e-6f);
      if (inter / uni > 0.5f) ssc[t] = -INFINITY;
    }
    if (V > VLDS) {
      for (int t = VLDS + tid; t < V; t += blockDim.x) {
        float4 b = *(const float4*)&bx[(size_t)t * 4];
        float offv = (float)lb[t] * 801.0f;
        float tx1 = b.x + offv, ty1 = b.y + offv, tx2 = b.z + offv, ty2 = b.w + offv;
        float ltx = fmaxf(tx1, bx1), lty = fmaxf(ty1, by1);
        float rbx = fminf(tx2, bx2), rby = fminf(ty2, by2);
        float inter = fmaxf(rbx - ltx, 0.0f) * fmaxf(rby - lty, 0.0f);
        float areat = (tx2 - tx1) * (ty2 - ty1);
        float uni = fmaxf(areat + barea - inter, 1e-6f);
        if (inter / uni > 0.5f) sc[t] = -INFINITY;
      }
    }
    __syncthreads();
  }
}

// ---------------- host ----------------
extern "C" void kernel_launch(void* const* d_in, const int* in_sizes, int n_in,
                              void* d_out, int out_size, void* d_ws, size_t ws_size,
                              hipStream_t stream) {
  const float* box_features = (const float*)d_in[0];
  const float* proposals    = (const float*)d_in[1];
  const float* fc6_w = (const float*)d_in[2];
  const float* fc6_b = (const float*)d_in[3];
  const float* fc7_w = (const float*)d_in[4];
  const float* fc7_b = (const float*)d_in[5];
  const float* cls_w = (const float*)d_in[6];
  const float* cls_b = (const float*)d_in[7];
  const float* bbox_w = (const float*)d_in[8];
  const float* bbox_b = (const float*)d_in[9];

  char* ws = (char*)d_ws;
  size_t off = 0;
  unsigned short* W6t  = (unsigned short*)(ws + off); off += (size_t)HID * FIN * 2;
  unsigned short* W7t  = (unsigned short*)(ws + off); off += (size_t)HID * HID * 2;
  unsigned short* Wcbt = (unsigned short*)(ws + off); off += (size_t)NCB * HID * 2;
  float* bias_cb       = (float*)(ws + off);          off += (size_t)NCB * 4;
  int*   ccount        = (int*)(ws + off);            off += 256;
  unsigned short* h1   = (unsigned short*)(ws + off); off += (size_t)MTOT * HID * 2;
  unsigned short* h2   = (unsigned short*)(ws + off); off += (size_t)MTOT * HID * 2;
  float* out3          = (float*)(ws + off);          off += (size_t)MTOT * NCB * 4;

  int CAP = CAPMAX;
  if (ws_size > off) {
    size_t avail = ws_size - off;
    size_t cap_ws = avail / 96;
    if (cap_ws < (size_t)CAP) CAP = (int)cap_ws;
  } else {
    CAP = 0;
  }
  float* cscore = (float*)(ws + off);
  int*   clabel = (int*)(ws + off + (size_t)NIMG * CAP * 4);
  float* cbox   = (float*)(ws + off + (size_t)NIMG * CAP * 8);

  // ---- weight prep ----
  transpose_cvt<<<dim3(HID / 32, FIN / 32), dim3(32, 8), 0, stream>>>(fc6_w, W6t, FIN, HID, 0, FIN);
  transpose_cvt<<<dim3(HID / 32, HID / 32), dim3(32, 8), 0, stream>>>(fc7_w, W7t, HID, HID, 0, HID);
  transpose_cvt<<<dim3(3,  HID / 32), dim3(32, 8), 0, stream>>>(cls_w,  Wcbt, HID, 91,  0,  HID);
  transpose_cvt<<<dim3(12, HID / 32), dim3(32, 8), 0, stream>>>(bbox_w, Wcbt, HID, 364, 91, HID);
  prep_misc<<<64, 256, 0, stream>>>(Wcbt, bias_cb, cls_b, bbox_b, ccount);

  // ---- MLP head + predictor (grid: m-tiles fastest for same-XCD A-slab sharing) ----
  gemm_nt<true,  true,  true ><<<dim3(MTOT / 128, HID / 128), 256, 0, stream>>>(
      box_features, W6t, fc6_b, h1, MTOT, HID, FIN);
  gemm_nt<false, true,  true ><<<dim3(MTOT / 128, HID / 128), 256, 0, stream>>>(
      h1, W7t, fc7_b, h2, MTOT, HID, HID);
  gemm_nt<false, false, false><<<dim3(MTOT / 128, NCB / 128), 256, 0, stream>>>(
      h2, Wcbt, bias_cb, out3, MTOT, NCB, HID);

  // ---- postprocess ----
  candgen<<<(MTOT * 64) / 256, 256, 0, stream>>>(out3, proposals, cscore, cbox, clabel, ccount, CAP);
  nms_kernel<<<NIMG, 256, 0, stream>>>(cscore, cbox, clabel, ccount, (float*)d_out, CAP);
}